// Round 3
// baseline (970.664 us; speedup 1.0000x reference)
//
#include <hip/hip_runtime.h>
#include <hip/hip_bf16.h>
#include <math.h>

typedef __attribute__((ext_vector_type(8))) short bf16x8;
typedef __attribute__((ext_vector_type(4))) float f32x4;
typedef unsigned short ushort_t;

#define T_SEQ 4096
#define C_DIM 1024
#define NH 16
#define HD 64

__device__ __forceinline__ ushort_t f2b(float f) {
  union { float f; unsigned u; } v; v.f = f;
  unsigned r = v.u + 0x7FFF + ((v.u >> 16) & 1);   // RNE
  return (ushort_t)(r >> 16);
}
__device__ __forceinline__ float b2f(ushort_t h) {
  union { unsigned u; float f; } v; v.u = ((unsigned)h) << 16; return v.f;
}

// ---------------- fused cast fp32 -> bf16 of all four weight mats -----------
__global__ __launch_bounds__(256) void cast_all(const float* __restrict__ w_qkv,
                                                const float* __restrict__ w_out,
                                                const float* __restrict__ w_fc1,
                                                const float* __restrict__ w_fc2,
                                                ushort_t* __restrict__ o_qkv,
                                                ushort_t* __restrict__ o_out,
                                                ushort_t* __restrict__ o_fc1,
                                                ushort_t* __restrict__ o_fc2) {
  const int n_qkv = 3 * C_DIM * C_DIM / 4, n_out = C_DIM * C_DIM / 4,
            n_fc  = 4 * C_DIM * C_DIM / 4;
  int i = blockIdx.x * 256 + threadIdx.x;
  int stride = gridDim.x * 256;
  int total = n_qkv + n_out + 2 * n_fc;
  for (; i < total; i += stride) {
    const float* src; ushort_t* dst; int j = i;
    if (j < n_qkv)            { src = w_qkv; dst = o_qkv; }
    else if ((j -= n_qkv) < n_out) { src = w_out; dst = o_out; }
    else if ((j -= n_out) < n_fc)  { src = w_fc1; dst = o_fc1; }
    else       { j -= n_fc;     src = w_fc2; dst = o_fc2; }
    float4 v = ((const float4*)src)[j];
    ushort4 o;
    o.x = f2b(v.x); o.y = f2b(v.y); o.z = f2b(v.z); o.w = f2b(v.w);
    ((ushort4*)dst)[j] = o;
  }
}

// ---------------- LayerNorm: fp32 [rows][1024] -> bf16 ----------------------
__global__ __launch_bounds__(256) void ln_kernel(const float* __restrict__ x,
                                                 const float* __restrict__ g,
                                                 const float* __restrict__ b,
                                                 ushort_t* __restrict__ out) {
  int row = blockIdx.x;
  int tid = threadIdx.x;
  float4 v = ((const float4*)(x + (size_t)row * C_DIM))[tid];
  float s  = v.x + v.y + v.z + v.w;
  float sq = v.x*v.x + v.y*v.y + v.z*v.z + v.w*v.w;
  #pragma unroll
  for (int m = 32; m >= 1; m >>= 1) {
    s  += __shfl_down(s, m, 64);
    sq += __shfl_down(sq, m, 64);
  }
  __shared__ float red[8];
  int wid = tid >> 6, lane = tid & 63;
  if (lane == 0) { red[wid] = s; red[wid + 4] = sq; }
  __syncthreads();
  s  = red[0] + red[1] + red[2] + red[3];
  sq = red[4] + red[5] + red[6] + red[7];
  float mu   = s * (1.0f / C_DIM);
  float var  = sq * (1.0f / C_DIM) - mu * mu;
  float rstd = rsqrtf(var + 1e-5f);
  float4 gg = ((const float4*)g)[tid];
  float4 bb = ((const float4*)b)[tid];
  ushort4 o;
  o.x = f2b((v.x - mu) * rstd * gg.x + bb.x);
  o.y = f2b((v.y - mu) * rstd * gg.y + bb.y);
  o.z = f2b((v.z - mu) * rstd * gg.z + bb.z);
  o.w = f2b((v.w - mu) * rstd * gg.w + bb.w);
  ((ushort4*)(out + (size_t)row * C_DIM))[tid] = o;
}

// ---------------- bf16 MFMA GEMM (m97-style staging) ------------------------
// C = A[M,K] @ B[K,N] + bias (+res) (+gelu)
// 128x128 tile, BK=64, 256 threads = 4 waves (2x2), each wave 64x64 = 4x4 frags
// A staged via global_load_lds width-16 into linear [128][64] (k-contiguous rows).
// B staged via bf16x8 reg loads, transposed into Bt[n][k] (stride 72).
template<bool GELU, bool OUT_F32, bool RES>
__global__ __launch_bounds__(256) void gemm_bf16(
    const ushort_t* __restrict__ A, const ushort_t* __restrict__ B,
    const float* __restrict__ bias, const float* __restrict__ res,
    float* __restrict__ outF, ushort_t* __restrict__ outB,
    int M, int N, int K) {
  __shared__ ushort_t As[128][64];   // linear (global_load_lds dest), rows k-contig
  __shared__ ushort_t Bt[128][72];   // transposed B: Bt[n][k], stride 72
  int tid  = threadIdx.x;
  int lane = tid & 63, w = tid >> 6;
  int wr = (w >> 1) * 64, wc = (w & 1) * 64;
  int brow = blockIdx.y * 128, bcol = blockIdx.x * 128;
  int l15 = lane & 15, lg = lane >> 4;

  f32x4 acc[4][4];
  #pragma unroll
  for (int m = 0; m < 4; ++m)
    #pragma unroll
    for (int n = 0; n < 4; ++n)
      acc[m][n] = (f32x4){0.f, 0.f, 0.f, 0.f};

  for (int k0 = 0; k0 < K; k0 += 64) {
    // ---- A: global_load_lds dwordx4; dest linear = idx*16 bytes ----
    #pragma unroll
    for (int it = 0; it < 4; ++it) {
      int idx = it * 256 + tid;            // 0..1023
      int r = idx >> 3, w8 = idx & 7;      // row, 8-bf16 chunk
      const ushort_t* src = A + (size_t)(brow + r) * K + k0 + w8 * 8;
      __builtin_amdgcn_global_load_lds(
          (const __attribute__((address_space(1))) unsigned*)src,
          (__attribute__((address_space(3))) unsigned*)&As[0][0] + idx * 4,
          16, 0, 0);
    }
    // ---- B: reg-stage bf16x8 (one k-row, 8 n's) then scatter to Bt[n][k] ----
    #pragma unroll
    for (int it = 0; it < 4; ++it) {
      int idx = it * 256 + tid;
      int kk = idx >> 4, n0 = (idx & 15) * 8;
      bf16x8 vv = *(const bf16x8*)(B + (size_t)(k0 + kk) * N + bcol + n0);
      #pragma unroll
      for (int e = 0; e < 8; ++e) Bt[n0 + e][kk] = ((ushort_t*)&vv)[e];
    }
    __syncthreads();
    #pragma unroll
    for (int half = 0; half < 2; ++half) {
      bf16x8 af[4], bfr[4];
      #pragma unroll
      for (int m = 0; m < 4; ++m)
        af[m] = *(const bf16x8*)&As[wr + m * 16 + l15][half * 32 + lg * 8];
      #pragma unroll
      for (int n = 0; n < 4; ++n)
        bfr[n] = *(const bf16x8*)&Bt[wc + n * 16 + l15][half * 32 + lg * 8];
      #pragma unroll
      for (int m = 0; m < 4; ++m)
        #pragma unroll
        for (int n = 0; n < 4; ++n)
          acc[m][n] = __builtin_amdgcn_mfma_f32_16x16x32_bf16(af[m], bfr[n], acc[m][n], 0, 0, 0);
    }
    __syncthreads();
  }

  // epilogue: C/D layout col=lane&15, row=(lane>>4)*4+reg  [HW-verified]
  #pragma unroll
  for (int m = 0; m < 4; ++m) {
    int row0 = brow + wr + m * 16 + lg * 4;
    #pragma unroll
    for (int n = 0; n < 4; ++n) {
      int col = bcol + wc + n * 16 + l15;
      float bv = bias[col];
      #pragma unroll
      for (int r = 0; r < 4; ++r) {
        int row = row0 + r;
        float v = acc[m][n][r] + bv;
        if (RES)  v += res[(size_t)row * N + col];
        if (GELU) v = 0.5f * v * (1.0f + erff(v * 0.70710678118f));
        if (OUT_F32) outF[(size_t)row * N + col] = v;
        else         outB[(size_t)row * N + col] = f2b(v);
      }
    }
  }
}

// ---------------- causal flash attention (unchanged this round) -------------
__global__ __launch_bounds__(256) void attn_kernel(const ushort_t* __restrict__ qkv,
                                                   ushort_t* __restrict__ out) {
  __shared__ ushort_t Kt[64][72];
  __shared__ ushort_t Vt[64][72];
  __shared__ ushort_t Pb[4][16][72];
  int h  = blockIdx.y;
  int qb = gridDim.x - 1 - blockIdx.x;
  int tid = threadIdx.x, lane = tid & 63, w = tid >> 6;
  int l15 = lane & 15, lg = lane >> 4;

  bf16x8 qf[2];
  {
    int qrow = qb * 64 + w * 16 + l15;
    const ushort_t* qp = qkv + (size_t)qrow * 3072 + h * 64;
    qf[0] = *(const bf16x8*)(qp + lg * 8);
    qf[1] = *(const bf16x8*)(qp + 32 + lg * 8);
  }
  float m_r[4], l_r[4];
  f32x4 o[4];
  #pragma unroll
  for (int r = 0; r < 4; ++r) { m_r[r] = -1e30f; l_r[r] = 0.f; }
  #pragma unroll
  for (int f = 0; f < 4; ++f) o[f] = (f32x4){0.f, 0.f, 0.f, 0.f};

  for (int s = 0; s <= qb; ++s) {
    for (int i = tid; i < 4096; i += 256) {
      int kv = i >> 6, d = i & 63;
      const ushort_t* base = qkv + (size_t)(s * 64 + kv) * 3072 + h * 64 + d;
      Kt[kv][d] = base[1024];
      Vt[d][kv] = base[2048];
    }
    __syncthreads();

    f32x4 sf[4];
    #pragma unroll
    for (int f = 0; f < 4; ++f) {
      bf16x8 k0 = *(const bf16x8*)&Kt[f * 16 + l15][lg * 8];
      bf16x8 k1 = *(const bf16x8*)&Kt[f * 16 + l15][32 + lg * 8];
      f32x4 a = (f32x4){0.f, 0.f, 0.f, 0.f};
      a = __builtin_amdgcn_mfma_f32_16x16x32_bf16(qf[0], k0, a, 0, 0, 0);
      a = __builtin_amdgcn_mfma_f32_16x16x32_bf16(qf[1], k1, a, 0, 0, 0);
      sf[f] = a;
    }

    float p[4][4];
    #pragma unroll
    for (int f = 0; f < 4; ++f)
      #pragma unroll
      for (int r = 0; r < 4; ++r) {
        float v = sf[f][r] * 0.125f;
        if (s == qb) {
          int rl = w * 16 + lg * 4 + r;
          int cl = f * 16 + l15;
          if (cl > rl) v = -1e30f;
        }
        p[f][r] = v;
      }

    #pragma unroll
    for (int r = 0; r < 4; ++r) {
      float mx = fmaxf(fmaxf(p[0][r], p[1][r]), fmaxf(p[2][r], p[3][r]));
      #pragma unroll
      for (int off = 1; off < 16; off <<= 1) mx = fmaxf(mx, __shfl_xor(mx, off, 64));
      float mn = fmaxf(m_r[r], mx);
      float sc = __expf(m_r[r] - mn);
      float sum = 0.f;
      #pragma unroll
      for (int f = 0; f < 4; ++f) { p[f][r] = __expf(p[f][r] - mn); sum += p[f][r]; }
      #pragma unroll
      for (int off = 1; off < 16; off <<= 1) sum += __shfl_xor(sum, off, 64);
      l_r[r] = l_r[r] * sc + sum;
      m_r[r] = mn;
      #pragma unroll
      for (int f = 0; f < 4; ++f) o[f][r] *= sc;
    }

    #pragma unroll
    for (int f = 0; f < 4; ++f)
      #pragma unroll
      for (int r = 0; r < 4; ++r)
        Pb[w][lg * 4 + r][f * 16 + l15] = f2b(p[f][r]);
    __syncthreads();

    bf16x8 pf0 = *(const bf16x8*)&Pb[w][l15][lg * 8];
    bf16x8 pf1 = *(const bf16x8*)&Pb[w][l15][32 + lg * 8];
    #pragma unroll
    for (int f = 0; f < 4; ++f) {
      bf16x8 v0 = *(const bf16x8*)&Vt[f * 16 + l15][lg * 8];
      bf16x8 v1 = *(const bf16x8*)&Vt[f * 16 + l15][32 + lg * 8];
      o[f] = __builtin_amdgcn_mfma_f32_16x16x32_bf16(pf0, v0, o[f], 0, 0, 0);
      o[f] = __builtin_amdgcn_mfma_f32_16x16x32_bf16(pf1, v1, o[f], 0, 0, 0);
    }
    __syncthreads();
  }

  #pragma unroll
  for (int f = 0; f < 4; ++f)
    #pragma unroll
    for (int r = 0; r < 4; ++r) {
      float v = o[f][r] / l_r[r];
      int row = qb * 64 + w * 16 + lg * 4 + r;
      out[(size_t)row * C_DIM + h * 64 + f * 16 + l15] = f2b(v);
    }
}

// ---------------------------------------------------------------------------
extern "C" void kernel_launch(void* const* d_in, const int* in_sizes, int n_in,
                              void* d_out, int out_size, void* d_ws, size_t ws_size,
                              hipStream_t stream) {
  const float* x     = (const float*)d_in[0];
  const float* ln1_g = (const float*)d_in[1];
  const float* ln1_b = (const float*)d_in[2];
  const float* w_qkv = (const float*)d_in[3];
  const float* b_qkv = (const float*)d_in[4];
  const float* w_out = (const float*)d_in[5];
  const float* b_out = (const float*)d_in[6];
  const float* ln2_g = (const float*)d_in[7];
  const float* ln2_b = (const float*)d_in[8];
  const float* w_fc1 = (const float*)d_in[9];
  const float* b_fc1 = (const float*)d_in[10];
  const float* w_fc2 = (const float*)d_in[11];
  const float* b_fc2 = (const float*)d_in[12];

  char* ws = (char*)d_ws;
  size_t off = 0;
  auto alloc = [&](size_t bytes) {
    void* p = ws + off;
    off = (off + bytes + 255) & ~(size_t)255;
    return p;
  };
  ushort_t* wqkv_b = (ushort_t*)alloc((size_t)C_DIM * 3 * C_DIM * 2);
  ushort_t* wout_b = (ushort_t*)alloc((size_t)C_DIM * C_DIM * 2);
  ushort_t* wfc1_b = (ushort_t*)alloc((size_t)C_DIM * 4 * C_DIM * 2);
  ushort_t* wfc2_b = (ushort_t*)alloc((size_t)4 * C_DIM * C_DIM * 2);
  ushort_t* xn1    = (ushort_t*)alloc((size_t)T_SEQ * C_DIM * 2);
  ushort_t* qkv    = (ushort_t*)alloc((size_t)T_SEQ * 3 * C_DIM * 2);
  ushort_t* attnO  = (ushort_t*)alloc((size_t)T_SEQ * C_DIM * 2);
  float*    x2     = (float*)   alloc((size_t)T_SEQ * C_DIM * 4);
  ushort_t* xn2    = (ushort_t*)alloc((size_t)T_SEQ * C_DIM * 2);
  ushort_t* hbuf   = (ushort_t*)alloc((size_t)T_SEQ * 4 * C_DIM * 2);
  (void)ws_size;

  // 1) fused weight casts
  cast_all<<<dim3(2048), 256, 0, stream>>>(w_qkv, w_out, w_fc1, w_fc2,
                                           wqkv_b, wout_b, wfc1_b, wfc2_b);

  // 2) LN1
  ln_kernel<<<dim3(T_SEQ), 256, 0, stream>>>(x, ln1_g, ln1_b, xn1);

  // 3) QKV GEMM
  gemm_bf16<false, false, false><<<dim3(24, 32), 256, 0, stream>>>(
      xn1, wqkv_b, b_qkv, nullptr, nullptr, qkv, T_SEQ, 3 * C_DIM, C_DIM);

  // 4) attention
  attn_kernel<<<dim3(T_SEQ / 64, NH), 256, 0, stream>>>(qkv, attnO);

  // 5) proj GEMM + residual(x) -> fp32 x2
  gemm_bf16<false, true, true><<<dim3(8, 32), 256, 0, stream>>>(
      attnO, wout_b, b_out, x, x2, nullptr, T_SEQ, C_DIM, C_DIM);

  // 6) LN2
  ln_kernel<<<dim3(T_SEQ), 256, 0, stream>>>(x2, ln2_g, ln2_b, xn2);

  // 7) FC1 GEMM + GELU
  gemm_bf16<true, false, false><<<dim3(32, 32), 256, 0, stream>>>(
      xn2, wfc1_b, b_fc1, nullptr, nullptr, hbuf, T_SEQ, 4 * C_DIM, C_DIM);

  // 8) FC2 GEMM + residual(x2) -> fp32 d_out
  gemm_bf16<false, true, true><<<dim3(8, 32), 256, 0, stream>>>(
      hbuf, wfc2_b, b_fc2, x2, (float*)d_out, nullptr, T_SEQ, C_DIM, 4 * C_DIM);
}

// Round 4
// 667.900 us; speedup vs baseline: 1.4533x; 1.4533x over previous
//
#include <hip/hip_runtime.h>
#include <hip/hip_bf16.h>
#include <math.h>

typedef __attribute__((ext_vector_type(8))) short bf16x8;
typedef __attribute__((ext_vector_type(4))) float f32x4;
typedef unsigned short ushort_t;

#define T_SEQ 4096
#define C_DIM 1024
#define NH 16
#define HD 64

__device__ __forceinline__ ushort_t f2b(float f) {
  union { float f; unsigned u; } v; v.f = f;
  unsigned r = v.u + 0x7FFF + ((v.u >> 16) & 1);   // RNE
  return (ushort_t)(r >> 16);
}

// ---------------- cast + transpose: W[K][N] fp32 -> WT[N][K] bf16 -----------
// 32x32 tiles, 256 threads.
__global__ __launch_bounds__(256) void cast_transpose(const float* __restrict__ W,
                                                      ushort_t* __restrict__ WT,
                                                      int K, int N) {
  __shared__ ushort_t tile[32][40];
  int n0 = blockIdx.x * 32, k0 = blockIdx.y * 32;
  int t = threadIdx.x;
  int kl = t >> 3, nl = (t & 7) * 4;
  float4 v = *(const float4*)(W + (size_t)(k0 + kl) * N + n0 + nl);
  ushort4 c;
  c.x = f2b(v.x); c.y = f2b(v.y); c.z = f2b(v.z); c.w = f2b(v.w);
  *(ushort4*)&tile[kl][nl] = c;
  __syncthreads();
  int nl2 = t >> 3, kl2 = (t & 7) * 4;
  ushort4 o;
  o.x = tile[kl2 + 0][nl2];
  o.y = tile[kl2 + 1][nl2];
  o.z = tile[kl2 + 2][nl2];
  o.w = tile[kl2 + 3][nl2];
  *(ushort4*)(WT + (size_t)(n0 + nl2) * K + k0 + kl2) = o;
}

// ---------------- LayerNorm: fp32 [rows][1024] -> bf16 ----------------------
__global__ __launch_bounds__(256) void ln_kernel(const float* __restrict__ x,
                                                 const float* __restrict__ g,
                                                 const float* __restrict__ b,
                                                 ushort_t* __restrict__ out) {
  int row = blockIdx.x;
  int tid = threadIdx.x;
  float4 v = ((const float4*)(x + (size_t)row * C_DIM))[tid];
  float s  = v.x + v.y + v.z + v.w;
  float sq = v.x*v.x + v.y*v.y + v.z*v.z + v.w*v.w;
  #pragma unroll
  for (int m = 32; m >= 1; m >>= 1) {
    s  += __shfl_down(s, m, 64);
    sq += __shfl_down(sq, m, 64);
  }
  __shared__ float red[8];
  int wid = tid >> 6, lane = tid & 63;
  if (lane == 0) { red[wid] = s; red[wid + 4] = sq; }
  __syncthreads();
  s  = red[0] + red[1] + red[2] + red[3];
  sq = red[4] + red[5] + red[6] + red[7];
  float mu   = s * (1.0f / C_DIM);
  float var  = sq * (1.0f / C_DIM) - mu * mu;
  float rstd = rsqrtf(var + 1e-5f);
  float4 gg = ((const float4*)g)[tid];
  float4 bb = ((const float4*)b)[tid];
  ushort4 o;
  o.x = f2b((v.x - mu) * rstd * gg.x + bb.x);
  o.y = f2b((v.y - mu) * rstd * gg.y + bb.y);
  o.z = f2b((v.z - mu) * rstd * gg.z + bb.z);
  o.w = f2b((v.w - mu) * rstd * gg.w + bb.w);
  ((ushort4*)(out + (size_t)row * C_DIM))[tid] = o;
}

// ---------------- bf16 MFMA GEMM, m97 structure -----------------------------
// C = A[M,K] @ BT[N,K]^T + bias (+res) (+gelu)
// 128x128 tile, BK=64, 256 thr = 4 waves (2x2), wave = 64x64 = 4x4 frags.
// BOTH tiles staged via global_load_lds width-16 into linear [128][64].
template<bool GELU, bool OUT_F32, bool RES>
__global__ __launch_bounds__(256) void gemm_bt(
    const ushort_t* __restrict__ A, const ushort_t* __restrict__ BT,
    const float* __restrict__ bias, const float* __restrict__ res,
    float* __restrict__ outF, ushort_t* __restrict__ outB,
    int M, int N, int K) {
  __shared__ ushort_t As[128][64];
  __shared__ ushort_t Bs[128][64];
  int tid  = threadIdx.x;
  int lane = tid & 63, w = tid >> 6;
  int wr = (w >> 1) * 64, wc = (w & 1) * 64;
  int brow = blockIdx.y * 128, bcol = blockIdx.x * 128;
  int l15 = lane & 15, lg = lane >> 4;

  f32x4 acc[4][4];
  #pragma unroll
  for (int m = 0; m < 4; ++m)
    #pragma unroll
    for (int n = 0; n < 4; ++n)
      acc[m][n] = (f32x4){0.f, 0.f, 0.f, 0.f};

  for (int k0 = 0; k0 < K; k0 += 64) {
    #pragma unroll
    for (int it = 0; it < 4; ++it) {
      int idx = it * 256 + tid;            // 0..1023: 128 rows x 8 chunks
      int r = idx >> 3, c = (idx & 7) * 8;
      __builtin_amdgcn_global_load_lds(
          (const __attribute__((address_space(1))) unsigned*)(A + (size_t)(brow + r) * K + k0 + c),
          (__attribute__((address_space(3))) unsigned*)&As[0][0] + idx * 4,
          16, 0, 0);
    }
    #pragma unroll
    for (int it = 0; it < 4; ++it) {
      int idx = it * 256 + tid;
      int r = idx >> 3, c = (idx & 7) * 8;
      __builtin_amdgcn_global_load_lds(
          (const __attribute__((address_space(1))) unsigned*)(BT + (size_t)(bcol + r) * K + k0 + c),
          (__attribute__((address_space(3))) unsigned*)&Bs[0][0] + idx * 4,
          16, 0, 0);
    }
    __syncthreads();
    #pragma unroll
    for (int half = 0; half < 2; ++half) {
      bf16x8 af[4], bfr[4];
      #pragma unroll
      for (int m = 0; m < 4; ++m)
        af[m] = *(const bf16x8*)&As[wr + m * 16 + l15][half * 32 + lg * 8];
      #pragma unroll
      for (int n = 0; n < 4; ++n)
        bfr[n] = *(const bf16x8*)&Bs[wc + n * 16 + l15][half * 32 + lg * 8];
      #pragma unroll
      for (int m = 0; m < 4; ++m)
        #pragma unroll
        for (int n = 0; n < 4; ++n)
          acc[m][n] = __builtin_amdgcn_mfma_f32_16x16x32_bf16(af[m], bfr[n], acc[m][n], 0, 0, 0);
    }
    __syncthreads();
  }

  // epilogue: C/D layout col=lane&15, row=(lane>>4)*4+reg  [HW-verified]
  #pragma unroll
  for (int m = 0; m < 4; ++m) {
    int row0 = brow + wr + m * 16 + lg * 4;
    #pragma unroll
    for (int n = 0; n < 4; ++n) {
      int col = bcol + wc + n * 16 + l15;
      float bv = bias[col];
      #pragma unroll
      for (int r = 0; r < 4; ++r) {
        int row = row0 + r;
        float v = acc[m][n][r] + bv;
        if (RES)  v += res[(size_t)row * N + col];
        if (GELU) v = 0.5f * v * (1.0f + erff(v * 0.70710678118f));
        if (OUT_F32) outF[(size_t)row * N + col] = v;
        else         outB[(size_t)row * N + col] = f2b(v);
      }
    }
  }
}

// ---------------- causal flash attention ------------------------------------
// Swizzled LDS: value K[r][c] lives at Ks[r][c ^ ((r&7)<<3)]; same for V^T.
// K staged via global_load_lds with pre-swizzled GLOBAL source (LDS linear).
// V reg-staged (bf16x8) with swizzled scatter writes.
__global__ __launch_bounds__(256) void attn_kernel(const ushort_t* __restrict__ qkv,
                                                   ushort_t* __restrict__ out) {
  __shared__ ushort_t Ks[64][64];
  __shared__ ushort_t Vs[64][64];        // Vs[d][kv'] , kv' = kv ^ ((d&7)<<3)
  __shared__ ushort_t Pb[4][16][72];
  int h  = blockIdx.y;
  int qb = gridDim.x - 1 - blockIdx.x;   // heavy blocks first
  int tid = threadIdx.x, lane = tid & 63, w = tid >> 6;
  int l15 = lane & 15, lg = lane >> 4;

  bf16x8 qf[2];
  {
    int qrow = qb * 64 + w * 16 + l15;
    const ushort_t* qp = qkv + (size_t)qrow * 3072 + h * 64;
    qf[0] = *(const bf16x8*)(qp + lg * 8);
    qf[1] = *(const bf16x8*)(qp + 32 + lg * 8);
  }
  float m_r[4], l_r[4];
  f32x4 o[4];
  #pragma unroll
  for (int r = 0; r < 4; ++r) { m_r[r] = -1e30f; l_r[r] = 0.f; }
  #pragma unroll
  for (int f = 0; f < 4; ++f) o[f] = (f32x4){0.f, 0.f, 0.f, 0.f};

  for (int s = 0; s <= qb; ++s) {
    const ushort_t* kbase = qkv + (size_t)(s * 64) * 3072 + h * 64 + 1024;
    const ushort_t* vbase = qkv + (size_t)(s * 64) * 3072 + h * 64 + 2048;
    // ---- K: global_load_lds, source pre-swizzled, LDS linear ----
    #pragma unroll
    for (int it = 0; it < 2; ++it) {
      int idx = it * 256 + tid;            // 0..511: 64 rows x 8 chunks
      int r = idx >> 3, ch = idx & 7;
      int srcc = (ch ^ (r & 7)) * 8;
      __builtin_amdgcn_global_load_lds(
          (const __attribute__((address_space(1))) unsigned*)(kbase + (size_t)r * 3072 + srcc),
          (__attribute__((address_space(3))) unsigned*)&Ks[0][0] + idx * 4,
          16, 0, 0);
    }
    // ---- V: bf16x8 reg loads, swizzled transpose scatter ----
    #pragma unroll
    for (int it = 0; it < 2; ++it) {
      int idx = it * 256 + tid;            // 0..511
      int kv = idx & 63, d0 = (idx >> 6) * 8;
      bf16x8 vv = *(const bf16x8*)(vbase + (size_t)kv * 3072 + d0);
      #pragma unroll
      for (int e = 0; e < 8; ++e)
        Vs[d0 + e][kv ^ (e << 3)] = ((ushort_t*)&vv)[e];   // (d0+e)&7 == e
    }
    __syncthreads();

    // ---- S = Q K^T ----
    f32x4 sf[4];
    #pragma unroll
    for (int f = 0; f < 4; ++f) {
      int row = f * 16 + l15;
      bf16x8 k0 = *(const bf16x8*)&Ks[row][((0 + lg) ^ (row & 7)) * 8];
      bf16x8 k1 = *(const bf16x8*)&Ks[row][((4 + lg) ^ (row & 7)) * 8];
      f32x4 a = (f32x4){0.f, 0.f, 0.f, 0.f};
      a = __builtin_amdgcn_mfma_f32_16x16x32_bf16(qf[0], k0, a, 0, 0, 0);
      a = __builtin_amdgcn_mfma_f32_16x16x32_bf16(qf[1], k1, a, 0, 0, 0);
      sf[f] = a;
    }

    float p[4][4];
    #pragma unroll
    for (int f = 0; f < 4; ++f)
      #pragma unroll
      for (int r = 0; r < 4; ++r) {
        float v = sf[f][r] * 0.125f;
        if (s == qb) {
          int rl = w * 16 + lg * 4 + r;
          int cl = f * 16 + l15;
          if (cl > rl) v = -1e30f;
        }
        p[f][r] = v;
      }

    #pragma unroll
    for (int r = 0; r < 4; ++r) {
      float mx = fmaxf(fmaxf(p[0][r], p[1][r]), fmaxf(p[2][r], p[3][r]));
      #pragma unroll
      for (int off = 1; off < 16; off <<= 1) mx = fmaxf(mx, __shfl_xor(mx, off, 64));
      float mn = fmaxf(m_r[r], mx);
      float sc = __expf(m_r[r] - mn);
      float sum = 0.f;
      #pragma unroll
      for (int f = 0; f < 4; ++f) { p[f][r] = __expf(p[f][r] - mn); sum += p[f][r]; }
      #pragma unroll
      for (int off = 1; off < 16; off <<= 1) sum += __shfl_xor(sum, off, 64);
      l_r[r] = l_r[r] * sc + sum;
      m_r[r] = mn;
      #pragma unroll
      for (int f = 0; f < 4; ++f) o[f][r] *= sc;
    }

    #pragma unroll
    for (int f = 0; f < 4; ++f)
      #pragma unroll
      for (int r = 0; r < 4; ++r)
        Pb[w][lg * 4 + r][f * 16 + l15] = f2b(p[f][r]);
    __syncthreads();

    // ---- O += P V ----
    bf16x8 pf0 = *(const bf16x8*)&Pb[w][l15][lg * 8];
    bf16x8 pf1 = *(const bf16x8*)&Pb[w][l15][32 + lg * 8];
    #pragma unroll
    for (int f = 0; f < 4; ++f) {
      int d = f * 16 + l15;
      bf16x8 v0 = *(const bf16x8*)&Vs[d][((0 + lg) ^ (d & 7)) * 8];
      bf16x8 v1 = *(const bf16x8*)&Vs[d][((4 + lg) ^ (d & 7)) * 8];
      o[f] = __builtin_amdgcn_mfma_f32_16x16x32_bf16(pf0, v0, o[f], 0, 0, 0);
      o[f] = __builtin_amdgcn_mfma_f32_16x16x32_bf16(pf1, v1, o[f], 0, 0, 0);
    }
    __syncthreads();
  }

  #pragma unroll
  for (int f = 0; f < 4; ++f)
    #pragma unroll
    for (int r = 0; r < 4; ++r) {
      float v = o[f][r] / l_r[r];
      int row = qb * 64 + w * 16 + lg * 4 + r;
      out[(size_t)row * C_DIM + h * 64 + f * 16 + l15] = f2b(v);
    }
}

// ---------------------------------------------------------------------------
extern "C" void kernel_launch(void* const* d_in, const int* in_sizes, int n_in,
                              void* d_out, int out_size, void* d_ws, size_t ws_size,
                              hipStream_t stream) {
  const float* x     = (const float*)d_in[0];
  const float* ln1_g = (const float*)d_in[1];
  const float* ln1_b = (const float*)d_in[2];
  const float* w_qkv = (const float*)d_in[3];
  const float* b_qkv = (const float*)d_in[4];
  const float* w_out = (const float*)d_in[5];
  const float* b_out = (const float*)d_in[6];
  const float* ln2_g = (const float*)d_in[7];
  const float* ln2_b = (const float*)d_in[8];
  const float* w_fc1 = (const float*)d_in[9];
  const float* b_fc1 = (const float*)d_in[10];
  const float* w_fc2 = (const float*)d_in[11];
  const float* b_fc2 = (const float*)d_in[12];

  char* ws = (char*)d_ws;
  size_t off = 0;
  auto alloc = [&](size_t bytes) {
    void* p = ws + off;
    off = (off + bytes + 255) & ~(size_t)255;
    return p;
  };
  // transposed bf16 weights
  ushort_t* wqkvT = (ushort_t*)alloc((size_t)3 * C_DIM * C_DIM * 2);  // [3072][1024]
  ushort_t* woutT = (ushort_t*)alloc((size_t)C_DIM * C_DIM * 2);      // [1024][1024]
  ushort_t* wfc1T = (ushort_t*)alloc((size_t)4 * C_DIM * C_DIM * 2);  // [4096][1024]
  ushort_t* wfc2T = (ushort_t*)alloc((size_t)C_DIM * 4 * C_DIM * 2);  // [1024][4096]
  ushort_t* xn1   = (ushort_t*)alloc((size_t)T_SEQ * C_DIM * 2);
  ushort_t* qkv   = (ushort_t*)alloc((size_t)T_SEQ * 3 * C_DIM * 2);
  ushort_t* attnO = (ushort_t*)alloc((size_t)T_SEQ * C_DIM * 2);
  float*    x2    = (float*)   alloc((size_t)T_SEQ * C_DIM * 4);
  ushort_t* xn2   = (ushort_t*)alloc((size_t)T_SEQ * C_DIM * 2);
  ushort_t* hbuf  = (ushort_t*)alloc((size_t)T_SEQ * 4 * C_DIM * 2);
  (void)ws_size;

  // 1) cast+transpose all weights: W[K][N] -> WT[N][K]
  cast_transpose<<<dim3(96, 32),  256, 0, stream>>>(w_qkv, wqkvT, C_DIM, 3 * C_DIM);
  cast_transpose<<<dim3(32, 32),  256, 0, stream>>>(w_out, woutT, C_DIM, C_DIM);
  cast_transpose<<<dim3(128, 32), 256, 0, stream>>>(w_fc1, wfc1T, C_DIM, 4 * C_DIM);
  cast_transpose<<<dim3(32, 128), 256, 0, stream>>>(w_fc2, wfc2T, 4 * C_DIM, C_DIM);

  // 2) LN1
  ln_kernel<<<dim3(T_SEQ), 256, 0, stream>>>(x, ln1_g, ln1_b, xn1);

  // 3) QKV GEMM
  gemm_bt<false, false, false><<<dim3(24, 32), 256, 0, stream>>>(
      xn1, wqkvT, b_qkv, nullptr, nullptr, qkv, T_SEQ, 3 * C_DIM, C_DIM);

  // 4) attention
  attn_kernel<<<dim3(T_SEQ / 64, NH), 256, 0, stream>>>(qkv, attnO);

  // 5) proj GEMM + residual(x) -> fp32 x2
  gemm_bt<false, true, true><<<dim3(8, 32), 256, 0, stream>>>(
      attnO, woutT, b_out, x, x2, nullptr, T_SEQ, C_DIM, C_DIM);

  // 6) LN2
  ln_kernel<<<dim3(T_SEQ), 256, 0, stream>>>(x2, ln2_g, ln2_b, xn2);

  // 7) FC1 GEMM + GELU
  gemm_bt<true, false, false><<<dim3(32, 32), 256, 0, stream>>>(
      xn2, wfc1T, b_fc1, nullptr, nullptr, hbuf, T_SEQ, 4 * C_DIM, C_DIM);

  // 8) FC2 GEMM + residual(x2) -> fp32 d_out
  gemm_bt<false, true, true><<<dim3(8, 32), 256, 0, stream>>>(
      hbuf, wfc2T, b_fc2, x2, (float*)d_out, nullptr, T_SEQ, C_DIM, 4 * C_DIM);
}

// Round 5
// 619.655 us; speedup vs baseline: 1.5665x; 1.0779x over previous
//
#include <hip/hip_runtime.h>
#include <hip/hip_bf16.h>
#include <math.h>

typedef __attribute__((ext_vector_type(8))) short bf16x8;
typedef __attribute__((ext_vector_type(4))) float f32x4;
typedef unsigned short ushort_t;

#define T_SEQ 4096
#define C_DIM 1024
#define NH 16
#define HD 64

__device__ __forceinline__ ushort_t f2b(float f) {
  union { float f; unsigned u; } v; v.f = f;
  unsigned r = v.u + 0x7FFF + ((v.u >> 16) & 1);   // RNE
  return (ushort_t)(r >> 16);
}

// ---------------- cast + transpose: W[K][N] fp32 -> WT[N][K] bf16 -----------
__global__ __launch_bounds__(256) void cast_transpose(const float* __restrict__ W,
                                                      ushort_t* __restrict__ WT,
                                                      int K, int N) {
  __shared__ ushort_t tile[32][40];
  int n0 = blockIdx.x * 32, k0 = blockIdx.y * 32;
  int t = threadIdx.x;
  int kl = t >> 3, nl = (t & 7) * 4;
  float4 v = *(const float4*)(W + (size_t)(k0 + kl) * N + n0 + nl);
  ushort4 c;
  c.x = f2b(v.x); c.y = f2b(v.y); c.z = f2b(v.z); c.w = f2b(v.w);
  *(ushort4*)&tile[kl][nl] = c;
  __syncthreads();
  int nl2 = t >> 3, kl2 = (t & 7) * 4;
  ushort4 o;
  o.x = tile[kl2 + 0][nl2];
  o.y = tile[kl2 + 1][nl2];
  o.z = tile[kl2 + 2][nl2];
  o.w = tile[kl2 + 3][nl2];
  *(ushort4*)(WT + (size_t)(n0 + nl2) * K + k0 + kl2) = o;
}

// ---------------- LayerNorm: fp32 [rows][1024] -> bf16 ----------------------
__global__ __launch_bounds__(256) void ln_kernel(const float* __restrict__ x,
                                                 const float* __restrict__ g,
                                                 const float* __restrict__ b,
                                                 ushort_t* __restrict__ out) {
  int row = blockIdx.x;
  int tid = threadIdx.x;
  float4 v = ((const float4*)(x + (size_t)row * C_DIM))[tid];
  float s  = v.x + v.y + v.z + v.w;
  float sq = v.x*v.x + v.y*v.y + v.z*v.z + v.w*v.w;
  #pragma unroll
  for (int m = 32; m >= 1; m >>= 1) {
    s  += __shfl_down(s, m, 64);
    sq += __shfl_down(sq, m, 64);
  }
  __shared__ float red[8];
  int wid = tid >> 6, lane = tid & 63;
  if (lane == 0) { red[wid] = s; red[wid + 4] = sq; }
  __syncthreads();
  s  = red[0] + red[1] + red[2] + red[3];
  sq = red[4] + red[5] + red[6] + red[7];
  float mu   = s * (1.0f / C_DIM);
  float var  = sq * (1.0f / C_DIM) - mu * mu;
  float rstd = rsqrtf(var + 1e-5f);
  float4 gg = ((const float4*)g)[tid];
  float4 bb = ((const float4*)b)[tid];
  ushort4 o;
  o.x = f2b((v.x - mu) * rstd * gg.x + bb.x);
  o.y = f2b((v.y - mu) * rstd * gg.y + bb.y);
  o.z = f2b((v.z - mu) * rstd * gg.z + bb.z);
  o.w = f2b((v.w - mu) * rstd * gg.w + bb.w);
  ((ushort4*)(out + (size_t)row * C_DIM))[tid] = o;
}

// ---------------- bf16 MFMA GEMM, m97 structure (unchanged) -----------------
template<bool GELU, bool OUT_F32, bool RES>
__global__ __launch_bounds__(256) void gemm_bt(
    const ushort_t* __restrict__ A, const ushort_t* __restrict__ BT,
    const float* __restrict__ bias, const float* __restrict__ res,
    float* __restrict__ outF, ushort_t* __restrict__ outB,
    int M, int N, int K) {
  __shared__ ushort_t As[128][64];
  __shared__ ushort_t Bs[128][64];
  int tid  = threadIdx.x;
  int lane = tid & 63, w = tid >> 6;
  int wr = (w >> 1) * 64, wc = (w & 1) * 64;
  int brow = blockIdx.y * 128, bcol = blockIdx.x * 128;
  int l15 = lane & 15, lg = lane >> 4;

  f32x4 acc[4][4];
  #pragma unroll
  for (int m = 0; m < 4; ++m)
    #pragma unroll
    for (int n = 0; n < 4; ++n)
      acc[m][n] = (f32x4){0.f, 0.f, 0.f, 0.f};

  for (int k0 = 0; k0 < K; k0 += 64) {
    #pragma unroll
    for (int it = 0; it < 4; ++it) {
      int idx = it * 256 + tid;
      int r = idx >> 3, c = (idx & 7) * 8;
      __builtin_amdgcn_global_load_lds(
          (const __attribute__((address_space(1))) unsigned*)(A + (size_t)(brow + r) * K + k0 + c),
          (__attribute__((address_space(3))) unsigned*)&As[0][0] + idx * 4,
          16, 0, 0);
    }
    #pragma unroll
    for (int it = 0; it < 4; ++it) {
      int idx = it * 256 + tid;
      int r = idx >> 3, c = (idx & 7) * 8;
      __builtin_amdgcn_global_load_lds(
          (const __attribute__((address_space(1))) unsigned*)(BT + (size_t)(bcol + r) * K + k0 + c),
          (__attribute__((address_space(3))) unsigned*)&Bs[0][0] + idx * 4,
          16, 0, 0);
    }
    __syncthreads();
    #pragma unroll
    for (int half = 0; half < 2; ++half) {
      bf16x8 af[4], bfr[4];
      #pragma unroll
      for (int m = 0; m < 4; ++m)
        af[m] = *(const bf16x8*)&As[wr + m * 16 + l15][half * 32 + lg * 8];
      #pragma unroll
      for (int n = 0; n < 4; ++n)
        bfr[n] = *(const bf16x8*)&Bs[wc + n * 16 + l15][half * 32 + lg * 8];
      #pragma unroll
      for (int m = 0; m < 4; ++m)
        #pragma unroll
        for (int n = 0; n < 4; ++n)
          acc[m][n] = __builtin_amdgcn_mfma_f32_16x16x32_bf16(af[m], bfr[n], acc[m][n], 0, 0, 0);
    }
    __syncthreads();
  }

  #pragma unroll
  for (int m = 0; m < 4; ++m) {
    int row0 = brow + wr + m * 16 + lg * 4;
    #pragma unroll
    for (int n = 0; n < 4; ++n) {
      int col = bcol + wc + n * 16 + l15;
      float bv = bias[col];
      #pragma unroll
      for (int r = 0; r < 4; ++r) {
        int row = row0 + r;
        float v = acc[m][n][r] + bv;
        if (RES)  v += res[(size_t)row * N + col];
        if (GELU) v = 0.5f * v * (1.0f + erff(v * 0.70710678118f));
        if (OUT_F32) outF[(size_t)row * N + col] = v;
        else         outB[(size_t)row * N + col] = f2b(v);
      }
    }
  }
}

// ---------------- causal flash attention, KVBLK=128, 2 barriers/tile --------
// Ks[r][c] holds K[r][c ^ ((r&7)<<3)] (staged via pre-swizzled gload_lds src).
// Vs[d][kv'] holds V^T with kv' = kv ^ ((d&7)<<3) (reg-stage + swizzled scatter).
// Pb is wave-private: no barrier needed between P write and PV read.
__global__ __launch_bounds__(256) void attn_kernel(const ushort_t* __restrict__ qkv,
                                                   ushort_t* __restrict__ out) {
  __shared__ ushort_t Ks[128][64];
  __shared__ ushort_t Vs[64][128];
  __shared__ ushort_t Pb[4][16][136];    // [wave][qrow][kv] stride 136 (272B, 16B-mult)
  int h  = blockIdx.y;
  int qb = gridDim.x - 1 - blockIdx.x;   // 0..63, heavy blocks first
  int tid = threadIdx.x, lane = tid & 63, w = tid >> 6;
  int l15 = lane & 15, lg = lane >> 4;

  bf16x8 qf[2];
  {
    int qrow = qb * 64 + w * 16 + l15;
    const ushort_t* qp = qkv + (size_t)qrow * 3072 + h * 64;
    qf[0] = *(const bf16x8*)(qp + lg * 8);
    qf[1] = *(const bf16x8*)(qp + 32 + lg * 8);
  }
  float m_r[4], l_r[4];
  f32x4 o[4];
  #pragma unroll
  for (int r = 0; r < 4; ++r) { m_r[r] = -1e30f; l_r[r] = 0.f; }
  #pragma unroll
  for (int f = 0; f < 4; ++f) o[f] = (f32x4){0.f, 0.f, 0.f, 0.f};

  int s_last = qb >> 1;
  for (int s = 0; s <= s_last; ++s) {
    const ushort_t* kbase = qkv + (size_t)(s * 128) * 3072 + h * 64 + 1024;
    const ushort_t* vbase = kbase + 1024;
    // ---- K: global_load_lds, pre-swizzled source, linear LDS dest ----
    #pragma unroll
    for (int it = 0; it < 4; ++it) {
      int idx = it * 256 + tid;            // 0..1023: 128 rows x 8 chunks
      int r = idx >> 3, ch = idx & 7;
      int srcc = (ch ^ (r & 7)) * 8;
      __builtin_amdgcn_global_load_lds(
          (const __attribute__((address_space(1))) unsigned*)(kbase + (size_t)r * 3072 + srcc),
          (__attribute__((address_space(3))) unsigned*)&Ks[0][0] + idx * 4,
          16, 0, 0);
    }
    // ---- V: bf16x8 reg loads, swizzled transpose scatter (per-lane kv) ----
    #pragma unroll
    for (int it = 0; it < 4; ++it) {
      int idx = it * 256 + tid;            // 0..1023
      int kv = (idx & 63) | ((idx >> 9) << 6);   // low6 per-lane, bit9 -> kv bit6
      int d0 = ((idx >> 6) & 7) * 8;
      bf16x8 vv = *(const bf16x8*)(vbase + (size_t)kv * 3072 + d0);
      #pragma unroll
      for (int e = 0; e < 8; ++e)
        Vs[d0 + e][kv ^ (e << 3)] = ((ushort_t*)&vv)[e];
    }
    __syncthreads();

    // ---- S = Q K^T : 8 col-frags of 16 ----
    f32x4 sf[8];
    #pragma unroll
    for (int f = 0; f < 8; ++f) {
      int row = f * 16 + l15;
      bf16x8 k0 = *(const bf16x8*)&Ks[row][(lg ^ (row & 7)) * 8];
      bf16x8 k1 = *(const bf16x8*)&Ks[row][((4 + lg) ^ (row & 7)) * 8];
      f32x4 a = (f32x4){0.f, 0.f, 0.f, 0.f};
      a = __builtin_amdgcn_mfma_f32_16x16x32_bf16(qf[0], k0, a, 0, 0, 0);
      a = __builtin_amdgcn_mfma_f32_16x16x32_bf16(qf[1], k1, a, 0, 0, 0);
      sf[f] = a;
    }

    // ---- scale + causal mask (global row/col compare, last tile only) ----
    float p[8][4];
    #pragma unroll
    for (int f = 0; f < 8; ++f)
      #pragma unroll
      for (int r = 0; r < 4; ++r) {
        float v = sf[f][r] * 0.125f;
        if (s == s_last) {
          int rl = qb * 64 + w * 16 + lg * 4 + r;
          int cl = s * 128 + f * 16 + l15;
          if (cl > rl) v = -1e30f;
        }
        p[f][r] = v;
      }

    // ---- online softmax (16-lane-group redundant per row) ----
    #pragma unroll
    for (int r = 0; r < 4; ++r) {
      float mx = p[0][r];
      #pragma unroll
      for (int f = 1; f < 8; ++f) mx = fmaxf(mx, p[f][r]);
      #pragma unroll
      for (int off = 1; off < 16; off <<= 1) mx = fmaxf(mx, __shfl_xor(mx, off, 64));
      float mn = fmaxf(m_r[r], mx);
      float sc = __expf(m_r[r] - mn);
      float sum = 0.f;
      #pragma unroll
      for (int f = 0; f < 8; ++f) { p[f][r] = __expf(p[f][r] - mn); sum += p[f][r]; }
      #pragma unroll
      for (int off = 1; off < 16; off <<= 1) sum += __shfl_xor(sum, off, 64);
      l_r[r] = l_r[r] * sc + sum;
      m_r[r] = mn;
      #pragma unroll
      for (int f = 0; f < 4; ++f) o[f][r] *= sc;
    }

    // ---- P -> wave-private LDS (no block barrier needed) ----
    #pragma unroll
    for (int f = 0; f < 8; ++f)
      #pragma unroll
      for (int r = 0; r < 4; ++r)
        Pb[w][lg * 4 + r][f * 16 + l15] = f2b(p[f][r]);

    // ---- O += P V  (k = 128 in 4 chunks of 32) ----
    #pragma unroll
    for (int kc = 0; kc < 4; ++kc) {
      bf16x8 pf = *(const bf16x8*)&Pb[w][l15][kc * 32 + lg * 8];
      #pragma unroll
      for (int f = 0; f < 4; ++f) {
        int d = f * 16 + l15;
        bf16x8 vf = *(const bf16x8*)&Vs[d][(((kc * 4) + lg) ^ (d & 7)) * 8];
        o[f] = __builtin_amdgcn_mfma_f32_16x16x32_bf16(pf, vf, o[f], 0, 0, 0);
      }
    }
    __syncthreads();
  }

  #pragma unroll
  for (int f = 0; f < 4; ++f)
    #pragma unroll
    for (int r = 0; r < 4; ++r) {
      float v = o[f][r] / l_r[r];
      int row = qb * 64 + w * 16 + lg * 4 + r;
      out[(size_t)row * C_DIM + h * 64 + f * 16 + l15] = f2b(v);
    }
}

// ---------------------------------------------------------------------------
extern "C" void kernel_launch(void* const* d_in, const int* in_sizes, int n_in,
                              void* d_out, int out_size, void* d_ws, size_t ws_size,
                              hipStream_t stream) {
  const float* x     = (const float*)d_in[0];
  const float* ln1_g = (const float*)d_in[1];
  const float* ln1_b = (const float*)d_in[2];
  const float* w_qkv = (const float*)d_in[3];
  const float* b_qkv = (const float*)d_in[4];
  const float* w_out = (const float*)d_in[5];
  const float* b_out = (const float*)d_in[6];
  const float* ln2_g = (const float*)d_in[7];
  const float* ln2_b = (const float*)d_in[8];
  const float* w_fc1 = (const float*)d_in[9];
  const float* b_fc1 = (const float*)d_in[10];
  const float* w_fc2 = (const float*)d_in[11];
  const float* b_fc2 = (const float*)d_in[12];

  char* ws = (char*)d_ws;
  size_t off = 0;
  auto alloc = [&](size_t bytes) {
    void* p = ws + off;
    off = (off + bytes + 255) & ~(size_t)255;
    return p;
  };
  ushort_t* wqkvT = (ushort_t*)alloc((size_t)3 * C_DIM * C_DIM * 2);
  ushort_t* woutT = (ushort_t*)alloc((size_t)C_DIM * C_DIM * 2);
  ushort_t* wfc1T = (ushort_t*)alloc((size_t)4 * C_DIM * C_DIM * 2);
  ushort_t* wfc2T = (ushort_t*)alloc((size_t)C_DIM * 4 * C_DIM * 2);
  ushort_t* xn1   = (ushort_t*)alloc((size_t)T_SEQ * C_DIM * 2);
  ushort_t* qkv   = (ushort_t*)alloc((size_t)T_SEQ * 3 * C_DIM * 2);
  ushort_t* attnO = (ushort_t*)alloc((size_t)T_SEQ * C_DIM * 2);
  float*    x2    = (float*)   alloc((size_t)T_SEQ * C_DIM * 4);
  ushort_t* xn2   = (ushort_t*)alloc((size_t)T_SEQ * C_DIM * 2);
  ushort_t* hbuf  = (ushort_t*)alloc((size_t)T_SEQ * 4 * C_DIM * 2);
  (void)ws_size;

  cast_transpose<<<dim3(96, 32),  256, 0, stream>>>(w_qkv, wqkvT, C_DIM, 3 * C_DIM);
  cast_transpose<<<dim3(32, 32),  256, 0, stream>>>(w_out, woutT, C_DIM, C_DIM);
  cast_transpose<<<dim3(128, 32), 256, 0, stream>>>(w_fc1, wfc1T, C_DIM, 4 * C_DIM);
  cast_transpose<<<dim3(32, 128), 256, 0, stream>>>(w_fc2, wfc2T, 4 * C_DIM, C_DIM);

  ln_kernel<<<dim3(T_SEQ), 256, 0, stream>>>(x, ln1_g, ln1_b, xn1);

  gemm_bt<false, false, false><<<dim3(24, 32), 256, 0, stream>>>(
      xn1, wqkvT, b_qkv, nullptr, nullptr, qkv, T_SEQ, 3 * C_DIM, C_DIM);

  attn_kernel<<<dim3(T_SEQ / 64, NH), 256, 0, stream>>>(qkv, attnO);

  gemm_bt<false, true, true><<<dim3(8, 32), 256, 0, stream>>>(
      attnO, woutT, b_out, x, x2, nullptr, T_SEQ, C_DIM, C_DIM);

  ln_kernel<<<dim3(T_SEQ), 256, 0, stream>>>(x2, ln2_g, ln2_b, xn2);

  gemm_bt<true, false, false><<<dim3(32, 32), 256, 0, stream>>>(
      xn2, wfc1T, b_fc1, nullptr, nullptr, hbuf, T_SEQ, 4 * C_DIM, C_DIM);

  gemm_bt<false, true, true><<<dim3(8, 32), 256, 0, stream>>>(
      hbuf, wfc2T, b_fc2, x2, (float*)d_out, nullptr, T_SEQ, C_DIM, 4 * C_DIM);
}